// Round 1
// baseline (539.096 us; speedup 1.0000x reference)
//
#include <hip/hip_runtime.h>
#include <hip/hip_bf16.h>

typedef __attribute__((ext_vector_type(8))) short bf16x8;
typedef __attribute__((ext_vector_type(4))) float f32x4;
typedef unsigned short u16;

#define T_TOK 2048
#define HID 4096
#define NH 32
#define NKV 8
#define HD 128
#define QKVN 6144   // (NH + 2*NKV) * HD
#define KOFF 4096   // k column offset in qkv
#define VOFF 5120   // v column offset in qkv

static __device__ __forceinline__ float bf2f(u16 x) {
    union { float f; unsigned u; } v; v.u = ((unsigned)x) << 16; return v.f;
}
static __device__ __forceinline__ u16 f2bf(float f) {
    union { float f; unsigned u; } v; v.f = f;
    unsigned u = v.u;
    unsigned r = (u + 0x7fff + ((u >> 16) & 1)) >> 16;
    return (u16)r;
}

// ---------------- elementwise f32 -> bf16 ----------------
__global__ __launch_bounds__(256) void convk(const float* __restrict__ in, u16* __restrict__ out) {
    int i = blockIdx.x * 256 + threadIdx.x;
    float4 v = ((const float4*)in)[i];
    ushort4 o;
    o.x = f2bf(v.x); o.y = f2bf(v.y); o.z = f2bf(v.z); o.w = f2bf(v.w);
    ((ushort4*)out)[i] = o;
}

// ---------------- transpose + convert: in f32 [R][C] -> out bf16 [C][R] ----------------
__global__ __launch_bounds__(256) void transpk(const float* __restrict__ in, u16* __restrict__ out,
                                               int R, int C) {
    __shared__ float tile[64][65];
    int c0 = blockIdx.x * 64, r0 = blockIdx.y * 64;
    int tid = threadIdx.x;
#pragma unroll
    for (int it = 0; it < 4; ++it) {
        int ci = it * 256 + tid;
        int r = ci >> 4, c4 = (ci & 15) * 4;
        float4 v = *(const float4*)&in[(size_t)(r0 + r) * C + c0 + c4];
        tile[r][c4 + 0] = v.x; tile[r][c4 + 1] = v.y; tile[r][c4 + 2] = v.z; tile[r][c4 + 3] = v.w;
    }
    __syncthreads();
#pragma unroll
    for (int it = 0; it < 4; ++it) {
        int ci = it * 256 + tid;
        int c = ci >> 4, rq = (ci & 15) * 4;
        ushort4 o;
        o.x = f2bf(tile[rq + 0][c]); o.y = f2bf(tile[rq + 1][c]);
        o.z = f2bf(tile[rq + 2][c]); o.w = f2bf(tile[rq + 3][c]);
        *(ushort4*)&out[(size_t)(c0 + c) * R + r0 + rq] = o;
    }
}

// ---------------- GEMM: C[M][N] = A[M][K] * Bt[N][K]^T, bf16 in, bf16 or f32 out ----------------
template <int OUTF32>
__global__ __launch_bounds__(256) void gemm_bt(const u16* __restrict__ A, const u16* __restrict__ Bt,
                                               void* __restrict__ Cout, int M, int N, int K) {
    __shared__ __attribute__((aligned(16))) u16 at[128 * 64];
    __shared__ __attribute__((aligned(16))) u16 bt[128 * 64];
    int m0 = blockIdx.y * 128, n0 = blockIdx.x * 128;
    int tid = threadIdx.x;
    int lane = tid & 63, wid = tid >> 6;
    int wr = wid >> 1, wc = wid & 1;
    int l15 = lane & 15, g = lane >> 4;

    f32x4 acc[4][4];
#pragma unroll
    for (int mi = 0; mi < 4; ++mi)
#pragma unroll
        for (int ni = 0; ni < 4; ++ni) acc[mi][ni] = (f32x4){0.f, 0.f, 0.f, 0.f};

    for (int kb = 0; kb < K; kb += 64) {
        __syncthreads();
#pragma unroll
        for (int it = 0; it < 4; ++it) {
            int ci = it * 256 + tid;
            int r = ci >> 3, c8 = (ci & 7) * 8;
            *(bf16x8*)&at[r * 64 + c8] = *(const bf16x8*)&A[(size_t)(m0 + r) * K + kb + c8];
            *(bf16x8*)&bt[r * 64 + c8] = *(const bf16x8*)&Bt[(size_t)(n0 + r) * K + kb + c8];
        }
        __syncthreads();
#pragma unroll
        for (int ks = 0; ks < 2; ++ks) {
            bf16x8 af[4], bfr[4];
#pragma unroll
            for (int mi = 0; mi < 4; ++mi)
                af[mi] = *(const bf16x8*)&at[(wr * 64 + mi * 16 + l15) * 64 + ks * 32 + g * 8];
#pragma unroll
            for (int ni = 0; ni < 4; ++ni)
                bfr[ni] = *(const bf16x8*)&bt[(wc * 64 + ni * 16 + l15) * 64 + ks * 32 + g * 8];
#pragma unroll
            for (int mi = 0; mi < 4; ++mi)
#pragma unroll
                for (int ni = 0; ni < 4; ++ni)
                    acc[mi][ni] = __builtin_amdgcn_mfma_f32_16x16x32_bf16(af[mi], bfr[ni], acc[mi][ni], 0, 0, 0);
        }
    }
#pragma unroll
    for (int mi = 0; mi < 4; ++mi)
#pragma unroll
        for (int ni = 0; ni < 4; ++ni)
#pragma unroll
            for (int i = 0; i < 4; ++i) {
                int row = m0 + wr * 64 + mi * 16 + g * 4 + i;
                int col = n0 + wc * 64 + ni * 16 + l15;
                float v = acc[mi][ni][i];
                if (OUTF32) ((float*)Cout)[(size_t)row * N + col] = v;
                else        ((u16*)Cout)[(size_t)row * N + col] = f2bf(v);
            }
}

// ---------------- RoPE in-place on q,k slices of qkv (bf16) ----------------
__global__ __launch_bounds__(256) void ropek(u16* __restrict__ qkvb, const int* __restrict__ positions) {
    int t = blockIdx.x;
    float pos = (float)positions[t];
#pragma unroll
    for (int it = 0; it < 10; ++it) {
        int ci = it * 256 + threadIdx.x;        // 2560 = (NH+NKV)*64
        int hh = ci >> 6, d = ci & 63;
        int base = (hh < NH) ? hh * HD : KOFF + (hh - NH) * HD;
        size_t off = (size_t)t * QKVN + base + d;
        float x1 = bf2f(qkvb[off]);
        float x2 = bf2f(qkvb[off + 64]);
        float inv = powf(1.0e6f, -(float)d * (1.0f / 64.0f));
        float fr = pos * inv;
        float s, c;
        __sincosf(fr, &s, &c);  // fast; refine with precise if accuracy demands
        s = sinf(fr); c = cosf(fr);
        qkvb[off]      = f2bf(x1 * c - x2 * s);
        qkvb[off + 64] = f2bf(x2 * c + x1 * s);
    }
}

// ---------------- V^T materialization: qkv v-slice -> vT[NKV][HD][T] ----------------
__global__ __launch_bounds__(256) void vtranspk(const u16* __restrict__ qkvb, u16* __restrict__ vT) {
    __shared__ __attribute__((aligned(16))) u16 tile[64][136];
    int kvh = blockIdx.x, t0 = blockIdx.y * 64;
    int tid = threadIdx.x;
#pragma unroll
    for (int it = 0; it < 4; ++it) {
        int ci = it * 256 + tid;
        int r = ci >> 4, c8 = (ci & 15) * 8;
        *(bf16x8*)&tile[r][c8] = *(const bf16x8*)&qkvb[(size_t)(t0 + r) * QKVN + VOFF + kvh * HD + c8];
    }
    __syncthreads();
#pragma unroll
    for (int it = 0; it < 4; ++it) {
        int ci = it * 256 + tid;
        int d = ci >> 3, tc = (ci & 7) * 8;
        union { bf16x8 v; u16 u[8]; } o;
#pragma unroll
        for (int e = 0; e < 8; ++e) o.u[e] = tile[tc + e][d];
        *(bf16x8*)&vT[((size_t)kvh * HD + d) * T_TOK + t0 + tc] = o.v;
    }
}

// ---------------- Flash attention: block = (head, 64 q rows), 4 waves x 16 rows ----------------
__global__ __launch_bounds__(256) void attnk(const u16* __restrict__ qkvb, const u16* __restrict__ vT,
                                             u16* __restrict__ attnb) {
    __shared__ __attribute__((aligned(16))) u16 kt_[64 * 136];
    __shared__ __attribute__((aligned(16))) u16 vt_[128 * 72];
    __shared__ __attribute__((aligned(16))) u16 pl_[4 * 16 * 72];
    int h = blockIdx.x, qt = blockIdx.y;
    int kvh = h >> 2;
    int q0 = qt * 64;
    int tid = threadIdx.x, lane = tid & 63, wid = tid >> 6;
    int l15 = lane & 15, g = lane >> 4;
    const float scale = 0.08838834764831845f;

    // Q fragments (held in registers for the whole block)
    bf16x8 qf[4];
    int qrow = q0 + wid * 16 + l15;
#pragma unroll
    for (int ks = 0; ks < 4; ++ks)
        qf[ks] = *(const bf16x8*)&qkvb[(size_t)qrow * QKVN + h * HD + ks * 32 + g * 8];

    f32x4 o[8];
#pragma unroll
    for (int df = 0; df < 8; ++df) o[df] = (f32x4){0.f, 0.f, 0.f, 0.f};
    float m_run[4], l_run[4];
#pragma unroll
    for (int i = 0; i < 4; ++i) { m_run[i] = -3.0e38f; l_run[i] = 0.f; }

    for (int kt2 = 0; kt2 <= qt; ++kt2) {
        int kvb = kt2 * 64;
        __syncthreads();
        // stage K tile [64][128] padded
#pragma unroll
        for (int it = 0; it < 4; ++it) {
            int ci = it * 256 + tid;
            int r = ci >> 4, c8 = (ci & 15) * 8;
            *(bf16x8*)&kt_[r * 136 + c8] =
                *(const bf16x8*)&qkvb[(size_t)(kvb + r) * QKVN + KOFF + kvh * HD + c8];
        }
        // stage V^T tile [128][64] padded
#pragma unroll
        for (int it = 0; it < 4; ++it) {
            int ci = it * 256 + tid;
            int d = ci >> 3, c8 = (ci & 7) * 8;
            *(bf16x8*)&vt_[d * 72 + c8] =
                *(const bf16x8*)&vT[((size_t)kvh * HD + d) * T_TOK + kvb + c8];
        }
        __syncthreads();

        // S = Q K^T  (per wave: 16 q rows x 64 kv cols)
        f32x4 s[4];
#pragma unroll
        for (int nf = 0; nf < 4; ++nf) s[nf] = (f32x4){0.f, 0.f, 0.f, 0.f};
#pragma unroll
        for (int ks = 0; ks < 4; ++ks) {
#pragma unroll
            for (int nf = 0; nf < 4; ++nf) {
                bf16x8 bfr = *(const bf16x8*)&kt_[(nf * 16 + l15) * 136 + ks * 32 + g * 8];
                s[nf] = __builtin_amdgcn_mfma_f32_16x16x32_bf16(qf[ks], bfr, s[nf], 0, 0, 0);
            }
        }

        // scale + causal mask + row max
        float mrow[4];
#pragma unroll
        for (int i = 0; i < 4; ++i) {
            int qr = q0 + wid * 16 + g * 4 + i;
            float mx = -3.0e38f;
#pragma unroll
            for (int nf = 0; nf < 4; ++nf) {
                int kvc = kvb + nf * 16 + l15;
                float v = s[nf][i] * scale;
                v = (kvc <= qr) ? v : -1.0e30f;
                s[nf][i] = v;
                mx = fmaxf(mx, v);
            }
            mrow[i] = mx;
        }
#pragma unroll
        for (int dd = 1; dd < 16; dd <<= 1)
#pragma unroll
            for (int i = 0; i < 4; ++i) mrow[i] = fmaxf(mrow[i], __shfl_xor(mrow[i], dd));

        float alpha[4];
#pragma unroll
        for (int i = 0; i < 4; ++i) {
            float mnew = fmaxf(m_run[i], mrow[i]);
            alpha[i] = __expf(m_run[i] - mnew);
            m_run[i] = mnew;
        }

        // P = exp(S - m), row sums, stash P to LDS (per-wave region)
        float rsum[4] = {0.f, 0.f, 0.f, 0.f};
#pragma unroll
        for (int nf = 0; nf < 4; ++nf)
#pragma unroll
            for (int i = 0; i < 4; ++i) {
                float p = __expf(s[nf][i] - m_run[i]);
                rsum[i] += p;
                pl_[wid * 1152 + (g * 4 + i) * 72 + nf * 16 + l15] = f2bf(p);
            }
#pragma unroll
        for (int dd = 1; dd < 16; dd <<= 1)
#pragma unroll
            for (int i = 0; i < 4; ++i) rsum[i] += __shfl_xor(rsum[i], dd);
#pragma unroll
        for (int i = 0; i < 4; ++i) l_run[i] = l_run[i] * alpha[i] + rsum[i];

        // rescale O
#pragma unroll
        for (int df = 0; df < 8; ++df)
#pragma unroll
            for (int i = 0; i < 4; ++i) o[df][i] *= alpha[i];

        // PV: O += P V   (A = P from LDS, B = V^T tile)
#pragma unroll
        for (int ks2 = 0; ks2 < 2; ++ks2) {
            bf16x8 af = *(const bf16x8*)&pl_[wid * 1152 + l15 * 72 + ks2 * 32 + g * 8];
#pragma unroll
            for (int df = 0; df < 8; ++df) {
                bf16x8 bfr = *(const bf16x8*)&vt_[(df * 16 + l15) * 72 + ks2 * 32 + g * 8];
                o[df] = __builtin_amdgcn_mfma_f32_16x16x32_bf16(af, bfr, o[df], 0, 0, 0);
            }
        }
    }

    // normalize + write
#pragma unroll
    for (int df = 0; df < 8; ++df)
#pragma unroll
        for (int i = 0; i < 4; ++i) {
            int qr = q0 + wid * 16 + g * 4 + i;
            int col = h * HD + df * 16 + l15;
            attnb[(size_t)qr * (NH * HD) + col] = f2bf(o[df][i] / l_run[i]);
        }
}

extern "C" void kernel_launch(void* const* d_in, const int* in_sizes, int n_in,
                              void* d_out, int out_size, void* d_ws, size_t ws_size,
                              hipStream_t stream) {
    const int*   positions = (const int*)d_in[0];
    const float* hs        = (const float*)d_in[1];
    const float* wqkv      = (const float*)d_in[2];
    const float* wo        = (const float*)d_in[3];
    float* out = (float*)d_out;

    char* ws = (char*)d_ws;
    // layout (bytes):
    u16* hsb   = (u16*)(ws);                                   // 16,777,216  (reused as attnb)
    u16* wqkvT = (u16*)(ws + 16777216);                        // 50,331,648
    u16* woT   = (u16*)(ws + 16777216 + 50331648);             // 33,554,432
    u16* qkvb  = (u16*)(ws + 16777216 + 50331648 + 33554432);  // 25,165,824
    u16* vT    = (u16*)(ws + 16777216 + 50331648 + 33554432 + 25165824); // 4,194,304
    u16* attnb = hsb;  // hs bf16 no longer needed after QKV GEMM

    // 1. converts / transposes
    convk<<<8192, 256, 0, stream>>>(hs, hsb);                       // 2048*4096 / 4 / 256
    transpk<<<dim3(96, 64), 256, 0, stream>>>(wqkv, wqkvT, HID, QKVN);
    transpk<<<dim3(64, 64), 256, 0, stream>>>(wo, woT, HID, HID);

    // 2. QKV GEMM -> bf16 qkv
    gemm_bt<0><<<dim3(48, 16), 256, 0, stream>>>(hsb, wqkvT, qkvb, T_TOK, QKVN, HID);

    // 3. RoPE in place on q,k
    ropek<<<T_TOK, 256, 0, stream>>>(qkvb, positions);

    // 4. V^T
    vtranspk<<<dim3(NKV, 32), 256, 0, stream>>>(qkvb, vT);

    // 5. attention
    attnk<<<dim3(NH, 32), 256, 0, stream>>>(qkvb, vT, attnb);

    // 6. output GEMM -> f32
    gemm_bt<1><<<dim3(32, 16), 256, 0, stream>>>(attnb, woT, out, T_TOK, HID, HID);
}

// Round 2
// 521.122 us; speedup vs baseline: 1.0345x; 1.0345x over previous
//
#include <hip/hip_runtime.h>
#include <hip/hip_bf16.h>

typedef __attribute__((ext_vector_type(8))) short bf16x8;
typedef __attribute__((ext_vector_type(4))) float f32x4;
typedef unsigned short u16;

#define T_TOK 2048
#define HID 4096
#define NH 32
#define NKV 8
#define HD 128
#define QKVN 6144   // (NH + 2*NKV) * HD
#define KOFF 4096   // k column offset in qkv
#define VOFF 5120   // v column offset in qkv

static __device__ __forceinline__ float bf2f(u16 x) {
    union { float f; unsigned u; } v; v.u = ((unsigned)x) << 16; return v.f;
}
static __device__ __forceinline__ u16 f2bf(float f) {
    union { float f; unsigned u; } v; v.f = f;
    unsigned u = v.u;
    unsigned r = (u + 0x7fff + ((u >> 16) & 1)) >> 16;
    return (u16)r;
}

// async global->LDS, 16B per lane; LDS dest = wave-uniform base + lane*16
static __device__ __forceinline__ void gload16(const u16* g, u16* l) {
    __builtin_amdgcn_global_load_lds((const __attribute__((address_space(1))) void*)g,
                                     (__attribute__((address_space(3))) void*)l, 16, 0, 0);
}

// ---------------- elementwise f32 -> bf16 ----------------
__global__ __launch_bounds__(256) void convk(const float* __restrict__ in, u16* __restrict__ out) {
    int i = blockIdx.x * 256 + threadIdx.x;
    float4 v = ((const float4*)in)[i];
    ushort4 o;
    o.x = f2bf(v.x); o.y = f2bf(v.y); o.z = f2bf(v.z); o.w = f2bf(v.w);
    ((ushort4*)out)[i] = o;
}

// ---------------- transpose + convert: in f32 [R][C] -> out bf16 [C][R] ----------------
__global__ __launch_bounds__(256) void transpk(const float* __restrict__ in, u16* __restrict__ out,
                                               int R, int C) {
    __shared__ float tile[64][65];
    int c0 = blockIdx.x * 64, r0 = blockIdx.y * 64;
    int tid = threadIdx.x;
#pragma unroll
    for (int it = 0; it < 4; ++it) {
        int ci = it * 256 + tid;
        int r = ci >> 4, c4 = (ci & 15) * 4;
        float4 v = *(const float4*)&in[(size_t)(r0 + r) * C + c0 + c4];
        tile[r][c4 + 0] = v.x; tile[r][c4 + 1] = v.y; tile[r][c4 + 2] = v.z; tile[r][c4 + 3] = v.w;
    }
    __syncthreads();
#pragma unroll
    for (int it = 0; it < 4; ++it) {
        int ci = it * 256 + tid;
        int c = ci >> 4, rq = (ci & 15) * 4;
        ushort4 o;
        o.x = f2bf(tile[rq + 0][c]); o.y = f2bf(tile[rq + 1][c]);
        o.z = f2bf(tile[rq + 2][c]); o.w = f2bf(tile[rq + 3][c]);
        *(ushort4*)&out[(size_t)(c0 + c) * R + r0 + rq] = o;
    }
}

// ---------------- GEMM: C[M][N] = A[M][K] * Bt[N][K]^T, bf16 in, bf16 or f32 out ----------
// m97 structure: 128x128 tile, BK=64, 4 waves, global_load_lds dwordx4 staging.
template <int OUTF32>
__global__ __launch_bounds__(256) void gemm_bt(const u16* __restrict__ A, const u16* __restrict__ Bt,
                                               void* __restrict__ Cout, int M, int N, int K) {
    __shared__ __attribute__((aligned(16))) u16 at[128 * 64];
    __shared__ __attribute__((aligned(16))) u16 bt[128 * 64];
    int m0 = blockIdx.y * 128, n0 = blockIdx.x * 128;
    int tid = threadIdx.x;
    int lane = tid & 63, wid = tid >> 6;
    int wr = wid >> 1, wc = wid & 1;
    int l15 = lane & 15, g = lane >> 4;

    // staging geometry: wave wid covers tile rows [wid*32, wid*32+32), 8 rows per call
    int srow = wid * 32 + (lane >> 3);      // + c*8 per call
    int scol = (lane & 7) * 8;              // element col within the 64-wide K-slab
    const u16* agp = &A[(size_t)(m0 + srow) * K + scol];
    const u16* bgp = &Bt[(size_t)(n0 + srow) * K + scol];

    f32x4 acc[4][4];
#pragma unroll
    for (int mi = 0; mi < 4; ++mi)
#pragma unroll
        for (int ni = 0; ni < 4; ++ni) acc[mi][ni] = (f32x4){0.f, 0.f, 0.f, 0.f};

    for (int kb = 0; kb < K; kb += 64) {
        __syncthreads();   // previous compute done before overwriting LDS
#pragma unroll
        for (int c = 0; c < 4; ++c) {
            gload16(agp + (size_t)(c * 8) * K + kb, &at[(wid * 32 + c * 8) * 64]);
            gload16(bgp + (size_t)(c * 8) * K + kb, &bt[(wid * 32 + c * 8) * 64]);
        }
        __syncthreads();   // vmcnt(0) drain -> tile ready
#pragma unroll
        for (int ks = 0; ks < 2; ++ks) {
            bf16x8 af[4], bfr[4];
#pragma unroll
            for (int mi = 0; mi < 4; ++mi)
                af[mi] = *(const bf16x8*)&at[(wr * 64 + mi * 16 + l15) * 64 + ks * 32 + g * 8];
#pragma unroll
            for (int ni = 0; ni < 4; ++ni)
                bfr[ni] = *(const bf16x8*)&bt[(wc * 64 + ni * 16 + l15) * 64 + ks * 32 + g * 8];
#pragma unroll
            for (int mi = 0; mi < 4; ++mi)
#pragma unroll
                for (int ni = 0; ni < 4; ++ni)
                    acc[mi][ni] = __builtin_amdgcn_mfma_f32_16x16x32_bf16(af[mi], bfr[ni], acc[mi][ni], 0, 0, 0);
        }
    }
#pragma unroll
    for (int mi = 0; mi < 4; ++mi)
#pragma unroll
        for (int ni = 0; ni < 4; ++ni)
#pragma unroll
            for (int i = 0; i < 4; ++i) {
                int row = m0 + wr * 64 + mi * 16 + g * 4 + i;
                int col = n0 + wc * 64 + ni * 16 + l15;
                float v = acc[mi][ni][i];
                if (OUTF32) ((float*)Cout)[(size_t)row * N + col] = v;
                else        ((u16*)Cout)[(size_t)row * N + col] = f2bf(v);
            }
}

// ---------------- RoPE in-place on q,k slices of qkv (bf16) ----------------
__global__ __launch_bounds__(256) void ropek(u16* __restrict__ qkvb, const int* __restrict__ positions) {
    int t = blockIdx.x;
    float pos = (float)positions[t];
#pragma unroll
    for (int it = 0; it < 10; ++it) {
        int ci = it * 256 + threadIdx.x;        // 2560 = (NH+NKV)*64
        int hh = ci >> 6, d = ci & 63;
        int base = (hh < NH) ? hh * HD : KOFF + (hh - NH) * HD;
        size_t off = (size_t)t * QKVN + base + d;
        float x1 = bf2f(qkvb[off]);
        float x2 = bf2f(qkvb[off + 64]);
        float inv = powf(1.0e6f, -(float)d * (1.0f / 64.0f));
        float fr = pos * inv;
        float s = sinf(fr), c = cosf(fr);
        qkvb[off]      = f2bf(x1 * c - x2 * s);
        qkvb[off + 64] = f2bf(x2 * c + x1 * s);
    }
}

// ---------------- V^T materialization: qkv v-slice -> vT[NKV][HD][T] ----------------
__global__ __launch_bounds__(256) void vtranspk(const u16* __restrict__ qkvb, u16* __restrict__ vT) {
    __shared__ __attribute__((aligned(16))) u16 tile[64][136];
    int kvh = blockIdx.x, t0 = blockIdx.y * 64;
    int tid = threadIdx.x;
#pragma unroll
    for (int it = 0; it < 4; ++it) {
        int ci = it * 256 + tid;
        int r = ci >> 4, c8 = (ci & 15) * 8;
        *(bf16x8*)&tile[r][c8] = *(const bf16x8*)&qkvb[(size_t)(t0 + r) * QKVN + VOFF + kvh * HD + c8];
    }
    __syncthreads();
#pragma unroll
    for (int it = 0; it < 4; ++it) {
        int ci = it * 256 + tid;
        int d = ci >> 3, tc = (ci & 7) * 8;
        union { bf16x8 v; u16 u[8]; } o;
#pragma unroll
        for (int e = 0; e < 8; ++e) o.u[e] = tile[tc + e][d];
        *(bf16x8*)&vT[((size_t)kvh * HD + d) * T_TOK + t0 + tc] = o.v;
    }
}

// ---------------- Flash attention: block = (head, 64 q rows), 4 waves x 16 rows ----------------
__global__ __launch_bounds__(256) void attnk(const u16* __restrict__ qkvb, const u16* __restrict__ vT,
                                             u16* __restrict__ attnb) {
    __shared__ __attribute__((aligned(16))) u16 kt_[64 * 136];
    __shared__ __attribute__((aligned(16))) u16 vt_[128 * 72];
    __shared__ __attribute__((aligned(16))) u16 pl_[4 * 16 * 72];
    int h = blockIdx.x, qt = blockIdx.y;
    int kvh = h >> 2;
    int q0 = qt * 64;
    int tid = threadIdx.x, lane = tid & 63, wid = tid >> 6;
    int l15 = lane & 15, g = lane >> 4;
    const float scale = 0.08838834764831845f;

    // Q fragments (held in registers for the whole block)
    bf16x8 qf[4];
    int qrow = q0 + wid * 16 + l15;
#pragma unroll
    for (int ks = 0; ks < 4; ++ks)
        qf[ks] = *(const bf16x8*)&qkvb[(size_t)qrow * QKVN + h * HD + ks * 32 + g * 8];

    f32x4 o[8];
#pragma unroll
    for (int df = 0; df < 8; ++df) o[df] = (f32x4){0.f, 0.f, 0.f, 0.f};
    float m_run[4], l_run[4];
#pragma unroll
    for (int i = 0; i < 4; ++i) { m_run[i] = -3.0e38f; l_run[i] = 0.f; }

    for (int kt2 = 0; kt2 <= qt; ++kt2) {
        int kvb = kt2 * 64;
        __syncthreads();
        // stage K tile [64][128] padded
#pragma unroll
        for (int it = 0; it < 4; ++it) {
            int ci = it * 256 + tid;
            int r = ci >> 4, c8 = (ci & 15) * 8;
            *(bf16x8*)&kt_[r * 136 + c8] =
                *(const bf16x8*)&qkvb[(size_t)(kvb + r) * QKVN + KOFF + kvh * HD + c8];
        }
        // stage V^T tile [128][64] padded
#pragma unroll
        for (int it = 0; it < 4; ++it) {
            int ci = it * 256 + tid;
            int d = ci >> 3, c8 = (ci & 7) * 8;
            *(bf16x8*)&vt_[d * 72 + c8] =
                *(const bf16x8*)&vT[((size_t)kvh * HD + d) * T_TOK + kvb + c8];
        }
        __syncthreads();

        // S = Q K^T  (per wave: 16 q rows x 64 kv cols)
        f32x4 s[4];
#pragma unroll
        for (int nf = 0; nf < 4; ++nf) s[nf] = (f32x4){0.f, 0.f, 0.f, 0.f};
#pragma unroll
        for (int ks = 0; ks < 4; ++ks) {
#pragma unroll
            for (int nf = 0; nf < 4; ++nf) {
                bf16x8 bfr = *(const bf16x8*)&kt_[(nf * 16 + l15) * 136 + ks * 32 + g * 8];
                s[nf] = __builtin_amdgcn_mfma_f32_16x16x32_bf16(qf[ks], bfr, s[nf], 0, 0, 0);
            }
        }

        // scale + causal mask + row max
        float mrow[4];
#pragma unroll
        for (int i = 0; i < 4; ++i) {
            int qr = q0 + wid * 16 + g * 4 + i;
            float mx = -3.0e38f;
#pragma unroll
            for (int nf = 0; nf < 4; ++nf) {
                int kvc = kvb + nf * 16 + l15;
                float v = s[nf][i] * scale;
                v = (kvc <= qr) ? v : -1.0e30f;
                s[nf][i] = v;
                mx = fmaxf(mx, v);
            }
            mrow[i] = mx;
        }
#pragma unroll
        for (int dd = 1; dd < 16; dd <<= 1)
#pragma unroll
            for (int i = 0; i < 4; ++i) mrow[i] = fmaxf(mrow[i], __shfl_xor(mrow[i], dd));

        float alpha[4];
#pragma unroll
        for (int i = 0; i < 4; ++i) {
            float mnew = fmaxf(m_run[i], mrow[i]);
            alpha[i] = __expf(m_run[i] - mnew);
            m_run[i] = mnew;
        }

        // P = exp(S - m), row sums, stash P to LDS (per-wave region)
        float rsum[4] = {0.f, 0.f, 0.f, 0.f};
#pragma unroll
        for (int nf = 0; nf < 4; ++nf)
#pragma unroll
            for (int i = 0; i < 4; ++i) {
                float p = __expf(s[nf][i] - m_run[i]);
                rsum[i] += p;
                pl_[wid * 1152 + (g * 4 + i) * 72 + nf * 16 + l15] = f2bf(p);
            }
#pragma unroll
        for (int dd = 1; dd < 16; dd <<= 1)
#pragma unroll
            for (int i = 0; i < 4; ++i) rsum[i] += __shfl_xor(rsum[i], dd);
#pragma unroll
        for (int i = 0; i < 4; ++i) l_run[i] = l_run[i] * alpha[i] + rsum[i];

        // rescale O
#pragma unroll
        for (int df = 0; df < 8; ++df)
#pragma unroll
            for (int i = 0; i < 4; ++i) o[df][i] *= alpha[i];

        // PV: O += P V   (A = P from LDS, B = V^T tile)
#pragma unroll
        for (int ks2 = 0; ks2 < 2; ++ks2) {
            bf16x8 af = *(const bf16x8*)&pl_[wid * 1152 + l15 * 72 + ks2 * 32 + g * 8];
#pragma unroll
            for (int df = 0; df < 8; ++df) {
                bf16x8 bfr = *(const bf16x8*)&vt_[(df * 16 + l15) * 72 + ks2 * 32 + g * 8];
                o[df] = __builtin_amdgcn_mfma_f32_16x16x32_bf16(af, bfr, o[df], 0, 0, 0);
            }
        }
    }

    // normalize + write
#pragma unroll
    for (int df = 0; df < 8; ++df)
#pragma unroll
        for (int i = 0; i < 4; ++i) {
            int qr = q0 + wid * 16 + g * 4 + i;
            int col = h * HD + df * 16 + l15;
            attnb[(size_t)qr * (NH * HD) + col] = f2bf(o[df][i] / l_run[i]);
        }
}

extern "C" void kernel_launch(void* const* d_in, const int* in_sizes, int n_in,
                              void* d_out, int out_size, void* d_ws, size_t ws_size,
                              hipStream_t stream) {
    const int*   positions = (const int*)d_in[0];
    const float* hs        = (const float*)d_in[1];
    const float* wqkv      = (const float*)d_in[2];
    const float* wo        = (const float*)d_in[3];
    float* out = (float*)d_out;

    char* ws = (char*)d_ws;
    // layout (bytes):
    u16* hsb   = (u16*)(ws);                                   // 16,777,216  (reused as attnb)
    u16* wqkvT = (u16*)(ws + 16777216);                        // 50,331,648
    u16* woT   = (u16*)(ws + 16777216 + 50331648);             // 33,554,432
    u16* qkvb  = (u16*)(ws + 16777216 + 50331648 + 33554432);  // 25,165,824
    u16* vT    = (u16*)(ws + 16777216 + 50331648 + 33554432 + 25165824); // 4,194,304
    u16* attnb = hsb;  // hs bf16 no longer needed after QKV GEMM

    // 1. converts / transposes
    convk<<<8192, 256, 0, stream>>>(hs, hsb);                       // 2048*4096 / 4 / 256
    transpk<<<dim3(96, 64), 256, 0, stream>>>(wqkv, wqkvT, HID, QKVN);
    transpk<<<dim3(64, 64), 256, 0, stream>>>(wo, woT, HID, HID);

    // 2. QKV GEMM -> bf16 qkv
    gemm_bt<0><<<dim3(48, 16), 256, 0, stream>>>(hsb, wqkvT, qkvb, T_TOK, QKVN, HID);

    // 3. RoPE in place on q,k
    ropek<<<T_TOK, 256, 0, stream>>>(qkvb, positions);

    // 4. V^T
    vtranspk<<<dim3(NKV, 32), 256, 0, stream>>>(qkvb, vT);

    // 5. attention
    attnk<<<dim3(NH, 32), 256, 0, stream>>>(qkvb, vT, attnb);

    // 6. output GEMM -> f32
    gemm_bt<1><<<dim3(32, 16), 256, 0, stream>>>(attnb, woT, out, T_TOK, HID, HID);
}

// Round 3
// 447.838 us; speedup vs baseline: 1.2038x; 1.1636x over previous
//
#include <hip/hip_runtime.h>
#include <hip/hip_bf16.h>

typedef __attribute__((ext_vector_type(8))) short bf16x8;
typedef __attribute__((ext_vector_type(4))) float f32x4;
typedef unsigned short u16;

#define T_TOK 2048
#define HID 4096
#define NH 32
#define NKV 8
#define HD 128
#define QKVN 6144   // (NH + 2*NKV) * HD
#define KOFF 4096   // k column offset in qkv
#define VOFF 5120   // v column offset in qkv

static __device__ __forceinline__ float bf2f(u16 x) {
    union { float f; unsigned u; } v; v.u = ((unsigned)x) << 16; return v.f;
}
static __device__ __forceinline__ u16 f2bf(float f) {
    union { float f; unsigned u; } v; v.f = f;
    unsigned u = v.u;
    unsigned r = (u + 0x7fff + ((u >> 16) & 1)) >> 16;
    return (u16)r;
}

// async global->LDS, 16B per lane; LDS dest = wave-uniform base + lane*16
static __device__ __forceinline__ void gload16(const u16* g, u16* l) {
    __builtin_amdgcn_global_load_lds((const __attribute__((address_space(1))) void*)g,
                                     (__attribute__((address_space(3))) void*)l, 16, 0, 0);
}

// ---------------- elementwise f32 -> bf16 ----------------
__global__ __launch_bounds__(256) void convk(const float* __restrict__ in, u16* __restrict__ out) {
    int i = blockIdx.x * 256 + threadIdx.x;
    float4 v = ((const float4*)in)[i];
    ushort4 o;
    o.x = f2bf(v.x); o.y = f2bf(v.y); o.z = f2bf(v.z); o.w = f2bf(v.w);
    ((ushort4*)out)[i] = o;
}

// ---------------- transpose + convert: in f32 [R][C] -> out bf16 [C][R] ----------------
__global__ __launch_bounds__(256) void transpk(const float* __restrict__ in, u16* __restrict__ out,
                                               int R, int C) {
    __shared__ float tile[64][65];
    int c0 = blockIdx.x * 64, r0 = blockIdx.y * 64;
    int tid = threadIdx.x;
#pragma unroll
    for (int it = 0; it < 4; ++it) {
        int ci = it * 256 + tid;
        int r = ci >> 4, c4 = (ci & 15) * 4;
        float4 v = *(const float4*)&in[(size_t)(r0 + r) * C + c0 + c4];
        tile[r][c4 + 0] = v.x; tile[r][c4 + 1] = v.y; tile[r][c4 + 2] = v.z; tile[r][c4 + 3] = v.w;
    }
    __syncthreads();
#pragma unroll
    for (int it = 0; it < 4; ++it) {
        int ci = it * 256 + tid;
        int c = ci >> 4, rq = (ci & 15) * 4;
        ushort4 o;
        o.x = f2bf(tile[rq + 0][c]); o.y = f2bf(tile[rq + 1][c]);
        o.z = f2bf(tile[rq + 2][c]); o.w = f2bf(tile[rq + 3][c]);
        *(ushort4*)&out[(size_t)(c0 + c) * R + r0 + rq] = o;
    }
}

// ---------------- GEMM: C[M][N] = A[M][K] * Bt[N][K]^T, bf16 in, bf16 or f32 out ----------
// m97 structure: 128x128 tile, BK=64, 4 waves, global_load_lds dwordx4 staging.
// T2 swizzle (both-sides, rule 21): LDS stays linear; global SOURCE slot is
// pre-permuted per lane (sg = (lane&7)^(lane>>3)), and fragment reads XOR the
// 16B-slot index with (row&7). 16-way bank conflict -> 2-way (free).
template <int OUTF32>
__global__ __launch_bounds__(256) void gemm_bt(const u16* __restrict__ A, const u16* __restrict__ Bt,
                                               void* __restrict__ Cout, int M, int N, int K) {
    __shared__ __attribute__((aligned(16))) u16 at[128 * 64];
    __shared__ __attribute__((aligned(16))) u16 bt[128 * 64];
    int m0 = blockIdx.y * 128, n0 = blockIdx.x * 128;
    int tid = threadIdx.x;
    int lane = tid & 63, wid = tid >> 6;
    int wr = wid >> 1, wc = wid & 1;
    int l15 = lane & 15, g = lane >> 4;
    int sw = lane & 7;                       // read-side XOR key (= row&7 of the rows this lane reads)

    // staging geometry: wave wid covers tile rows [wid*32, wid*32+32), 8 rows per call.
    // LDS dest is linear (base + lane*16): row = r0 + (lane>>3), slot = lane&7.
    // That LDS slot must hold global slot (lane&7) ^ (row&7) = (lane&7) ^ (lane>>3).
    int srow = wid * 32 + (lane >> 3);
    int scol = ((lane & 7) ^ (lane >> 3)) * 8;   // swizzled global 16B-slot
    const u16* agp = &A[(size_t)(m0 + srow) * K + scol];
    const u16* bgp = &Bt[(size_t)(n0 + srow) * K + scol];

    f32x4 acc[4][4];
#pragma unroll
    for (int mi = 0; mi < 4; ++mi)
#pragma unroll
        for (int ni = 0; ni < 4; ++ni) acc[mi][ni] = (f32x4){0.f, 0.f, 0.f, 0.f};

    for (int kb = 0; kb < K; kb += 64) {
        __syncthreads();   // previous compute done before overwriting LDS
#pragma unroll
        for (int c = 0; c < 4; ++c) {
            gload16(agp + (size_t)(c * 8) * K + kb, &at[(wid * 32 + c * 8) * 64]);
            gload16(bgp + (size_t)(c * 8) * K + kb, &bt[(wid * 32 + c * 8) * 64]);
        }
        __syncthreads();   // vmcnt(0) drain -> tile ready
#pragma unroll
        for (int ks = 0; ks < 2; ++ks) {
            bf16x8 af[4], bfr[4];
#pragma unroll
            for (int mi = 0; mi < 4; ++mi)
                af[mi] = *(const bf16x8*)&at[(wr * 64 + mi * 16 + l15) * 64 + (((ks * 4 + g) ^ sw) * 8)];
#pragma unroll
            for (int ni = 0; ni < 4; ++ni)
                bfr[ni] = *(const bf16x8*)&bt[(wc * 64 + ni * 16 + l15) * 64 + (((ks * 4 + g) ^ sw) * 8)];
#pragma unroll
            for (int mi = 0; mi < 4; ++mi)
#pragma unroll
                for (int ni = 0; ni < 4; ++ni)
                    acc[mi][ni] = __builtin_amdgcn_mfma_f32_16x16x32_bf16(af[mi], bfr[ni], acc[mi][ni], 0, 0, 0);
        }
    }
#pragma unroll
    for (int mi = 0; mi < 4; ++mi)
#pragma unroll
        for (int ni = 0; ni < 4; ++ni)
#pragma unroll
            for (int i = 0; i < 4; ++i) {
                int row = m0 + wr * 64 + mi * 16 + g * 4 + i;
                int col = n0 + wc * 64 + ni * 16 + l15;
                float v = acc[mi][ni][i];
                if (OUTF32) ((float*)Cout)[(size_t)row * N + col] = v;
                else        ((u16*)Cout)[(size_t)row * N + col] = f2bf(v);
            }
}

// ---------------- RoPE in-place on q,k slices of qkv (bf16) ----------------
__global__ __launch_bounds__(256) void ropek(u16* __restrict__ qkvb, const int* __restrict__ positions) {
    int t = blockIdx.x;
    float pos = (float)positions[t];
#pragma unroll
    for (int it = 0; it < 10; ++it) {
        int ci = it * 256 + threadIdx.x;        // 2560 = (NH+NKV)*64
        int hh = ci >> 6, d = ci & 63;
        int base = (hh < NH) ? hh * HD : KOFF + (hh - NH) * HD;
        size_t off = (size_t)t * QKVN + base + d;
        float x1 = bf2f(qkvb[off]);
        float x2 = bf2f(qkvb[off + 64]);
        float inv = powf(1.0e6f, -(float)d * (1.0f / 64.0f));
        float fr = pos * inv;
        float s = sinf(fr), c = cosf(fr);
        qkvb[off]      = f2bf(x1 * c - x2 * s);
        qkvb[off + 64] = f2bf(x2 * c + x1 * s);
    }
}

// ---------------- V^T materialization: qkv v-slice -> vT[NKV][HD][T] ----------------
__global__ __launch_bounds__(256) void vtranspk(const u16* __restrict__ qkvb, u16* __restrict__ vT) {
    __shared__ __attribute__((aligned(16))) u16 tile[64][136];
    int kvh = blockIdx.x, t0 = blockIdx.y * 64;
    int tid = threadIdx.x;
#pragma unroll
    for (int it = 0; it < 4; ++it) {
        int ci = it * 256 + tid;
        int r = ci >> 4, c8 = (ci & 15) * 8;
        *(bf16x8*)&tile[r][c8] = *(const bf16x8*)&qkvb[(size_t)(t0 + r) * QKVN + VOFF + kvh * HD + c8];
    }
    __syncthreads();
#pragma unroll
    for (int it = 0; it < 4; ++it) {
        int ci = it * 256 + tid;
        int d = ci >> 3, tc = (ci & 7) * 8;
        union { bf16x8 v; u16 u[8]; } o;
#pragma unroll
        for (int e = 0; e < 8; ++e) o.u[e] = tile[tc + e][d];
        *(bf16x8*)&vT[((size_t)kvh * HD + d) * T_TOK + t0 + tc] = o.v;
    }
}

// ---------------- Flash attention: block = (head, 64 q rows), 4 waves x 16 rows ----------------
__global__ __launch_bounds__(256) void attnk(const u16* __restrict__ qkvb, const u16* __restrict__ vT,
                                             u16* __restrict__ attnb) {
    __shared__ __attribute__((aligned(16))) u16 kt_[64 * 136];
    __shared__ __attribute__((aligned(16))) u16 vt_[128 * 72];
    __shared__ __attribute__((aligned(16))) u16 pl_[4 * 16 * 72];
    int h = blockIdx.x, qt = blockIdx.y;
    int kvh = h >> 2;
    int q0 = qt * 64;
    int tid = threadIdx.x, lane = tid & 63, wid = tid >> 6;
    int l15 = lane & 15, g = lane >> 4;
    const float scale = 0.08838834764831845f;

    // Q fragments (held in registers for the whole block)
    bf16x8 qf[4];
    int qrow = q0 + wid * 16 + l15;
#pragma unroll
    for (int ks = 0; ks < 4; ++ks)
        qf[ks] = *(const bf16x8*)&qkvb[(size_t)qrow * QKVN + h * HD + ks * 32 + g * 8];

    f32x4 o[8];
#pragma unroll
    for (int df = 0; df < 8; ++df) o[df] = (f32x4){0.f, 0.f, 0.f, 0.f};
    float m_run[4], l_run[4];
#pragma unroll
    for (int i = 0; i < 4; ++i) { m_run[i] = -3.0e38f; l_run[i] = 0.f; }

    for (int kt2 = 0; kt2 <= qt; ++kt2) {
        int kvb = kt2 * 64;
        __syncthreads();
        // stage K tile [64][128] padded
#pragma unroll
        for (int it = 0; it < 4; ++it) {
            int ci = it * 256 + tid;
            int r = ci >> 4, c8 = (ci & 15) * 8;
            *(bf16x8*)&kt_[r * 136 + c8] =
                *(const bf16x8*)&qkvb[(size_t)(kvb + r) * QKVN + KOFF + kvh * HD + c8];
        }
        // stage V^T tile [128][64] padded
#pragma unroll
        for (int it = 0; it < 4; ++it) {
            int ci = it * 256 + tid;
            int d = ci >> 3, c8 = (ci & 7) * 8;
            *(bf16x8*)&vt_[d * 72 + c8] =
                *(const bf16x8*)&vT[((size_t)kvh * HD + d) * T_TOK + kvb + c8];
        }
        __syncthreads();

        // S = Q K^T  (per wave: 16 q rows x 64 kv cols)
        f32x4 s[4];
#pragma unroll
        for (int nf = 0; nf < 4; ++nf) s[nf] = (f32x4){0.f, 0.f, 0.f, 0.f};
#pragma unroll
        for (int ks = 0; ks < 4; ++ks) {
#pragma unroll
            for (int nf = 0; nf < 4; ++nf) {
                bf16x8 bfr = *(const bf16x8*)&kt_[(nf * 16 + l15) * 136 + ks * 32 + g * 8];
                s[nf] = __builtin_amdgcn_mfma_f32_16x16x32_bf16(qf[ks], bfr, s[nf], 0, 0, 0);
            }
        }

        // scale + causal mask + row max
        float mrow[4];
#pragma unroll
        for (int i = 0; i < 4; ++i) {
            int qr = q0 + wid * 16 + g * 4 + i;
            float mx = -3.0e38f;
#pragma unroll
            for (int nf = 0; nf < 4; ++nf) {
                int kvc = kvb + nf * 16 + l15;
                float v = s[nf][i] * scale;
                v = (kvc <= qr) ? v : -1.0e30f;
                s[nf][i] = v;
                mx = fmaxf(mx, v);
            }
            mrow[i] = mx;
        }
#pragma unroll
        for (int dd = 1; dd < 16; dd <<= 1)
#pragma unroll
            for (int i = 0; i < 4; ++i) mrow[i] = fmaxf(mrow[i], __shfl_xor(mrow[i], dd));

        float alpha[4];
#pragma unroll
        for (int i = 0; i < 4; ++i) {
            float mnew = fmaxf(m_run[i], mrow[i]);
            alpha[i] = __expf(m_run[i] - mnew);
            m_run[i] = mnew;
        }

        // P = exp(S - m), row sums, stash P to LDS (per-wave region)
        float rsum[4] = {0.f, 0.f, 0.f, 0.f};
#pragma unroll
        for (int nf = 0; nf < 4; ++nf)
#pragma unroll
            for (int i = 0; i < 4; ++i) {
                float p = __expf(s[nf][i] - m_run[i]);
                rsum[i] += p;
                pl_[wid * 1152 + (g * 4 + i) * 72 + nf * 16 + l15] = f2bf(p);
            }
#pragma unroll
        for (int dd = 1; dd < 16; dd <<= 1)
#pragma unroll
            for (int i = 0; i < 4; ++i) rsum[i] += __shfl_xor(rsum[i], dd);
#pragma unroll
        for (int i = 0; i < 4; ++i) l_run[i] = l_run[i] * alpha[i] + rsum[i];

        // rescale O
#pragma unroll
        for (int df = 0; df < 8; ++df)
#pragma unroll
            for (int i = 0; i < 4; ++i) o[df][i] *= alpha[i];

        // PV: O += P V   (A = P from LDS, B = V^T tile)
#pragma unroll
        for (int ks2 = 0; ks2 < 2; ++ks2) {
            bf16x8 af = *(const bf16x8*)&pl_[wid * 1152 + l15 * 72 + ks2 * 32 + g * 8];
#pragma unroll
            for (int df = 0; df < 8; ++df) {
                bf16x8 bfr = *(const bf16x8*)&vt_[(df * 16 + l15) * 72 + ks2 * 32 + g * 8];
                o[df] = __builtin_amdgcn_mfma_f32_16x16x32_bf16(af, bfr, o[df], 0, 0, 0);
            }
        }
    }

    // normalize + write
#pragma unroll
    for (int df = 0; df < 8; ++df)
#pragma unroll
        for (int i = 0; i < 4; ++i) {
            int qr = q0 + wid * 16 + g * 4 + i;
            int col = h * HD + df * 16 + l15;
            attnb[(size_t)qr * (NH * HD) + col] = f2bf(o[df][i] / l_run[i]);
        }
}

extern "C" void kernel_launch(void* const* d_in, const int* in_sizes, int n_in,
                              void* d_out, int out_size, void* d_ws, size_t ws_size,
                              hipStream_t stream) {
    const int*   positions = (const int*)d_in[0];
    const float* hs        = (const float*)d_in[1];
    const float* wqkv      = (const float*)d_in[2];
    const float* wo        = (const float*)d_in[3];
    float* out = (float*)d_out;

    char* ws = (char*)d_ws;
    // layout (bytes):
    u16* hsb   = (u16*)(ws);                                   // 16,777,216  (reused as attnb)
    u16* wqkvT = (u16*)(ws + 16777216);                        // 50,331,648
    u16* woT   = (u16*)(ws + 16777216 + 50331648);             // 33,554,432
    u16* qkvb  = (u16*)(ws + 16777216 + 50331648 + 33554432);  // 25,165,824
    u16* vT    = (u16*)(ws + 16777216 + 50331648 + 33554432 + 25165824); // 4,194,304
    u16* attnb = hsb;  // hs bf16 no longer needed after QKV GEMM

    // 1. converts / transposes
    convk<<<8192, 256, 0, stream>>>(hs, hsb);                       // 2048*4096 / 4 / 256
    transpk<<<dim3(96, 64), 256, 0, stream>>>(wqkv, wqkvT, HID, QKVN);
    transpk<<<dim3(64, 64), 256, 0, stream>>>(wo, woT, HID, HID);

    // 2. QKV GEMM -> bf16 qkv
    gemm_bt<0><<<dim3(48, 16), 256, 0, stream>>>(hsb, wqkvT, qkvb, T_TOK, QKVN, HID);

    // 3. RoPE in place on q,k
    ropek<<<T_TOK, 256, 0, stream>>>(qkvb, positions);

    // 4. V^T
    vtranspk<<<dim3(NKV, 32), 256, 0, stream>>>(qkvb, vT);

    // 5. attention
    attnk<<<dim3(NH, 32), 256, 0, stream>>>(qkvb, vT, attnb);

    // 6. output GEMM -> f32
    gemm_bt<1><<<dim3(32, 16), 256, 0, stream>>>(attnb, woT, out, T_TOK, HID, HID);
}

// Round 4
// 371.393 us; speedup vs baseline: 1.4516x; 1.2058x over previous
//
#include <hip/hip_runtime.h>
#include <hip/hip_bf16.h>

typedef __attribute__((ext_vector_type(8))) short bf16x8;
typedef __attribute__((ext_vector_type(4))) float f32x4;
typedef unsigned short u16;

#define T_TOK 2048
#define HID 4096
#define NH 32
#define NKV 8
#define HD 128
#define QKVN 6144   // (NH + 2*NKV) * HD
#define KOFF 4096   // k column offset in qkv
#define VOFF 5120   // v column offset in qkv

static __device__ __forceinline__ float bf2f(u16 x) {
    union { float f; unsigned u; } v; v.u = ((unsigned)x) << 16; return v.f;
}
static __device__ __forceinline__ u16 f2bf(float f) {
    union { float f; unsigned u; } v; v.f = f;
    unsigned u = v.u;
    unsigned r = (u + 0x7fff + ((u >> 16) & 1)) >> 16;
    return (u16)r;
}

// async global->LDS, 16B per lane; LDS dest = wave-uniform base + lane*16
static __device__ __forceinline__ void gload16(const u16* g, u16* l) {
    __builtin_amdgcn_global_load_lds((const __attribute__((address_space(1))) void*)g,
                                     (__attribute__((address_space(3))) void*)l, 16, 0, 0);
}

// ---------------- elementwise f32 -> bf16 ----------------
__global__ __launch_bounds__(256) void convk(const float* __restrict__ in, u16* __restrict__ out) {
    int i = blockIdx.x * 256 + threadIdx.x;
    float4 v = ((const float4*)in)[i];
    ushort4 o;
    o.x = f2bf(v.x); o.y = f2bf(v.y); o.z = f2bf(v.z); o.w = f2bf(v.w);
    ((ushort4*)out)[i] = o;
}

// ---------------- transpose + convert: in f32 [R][C] -> out bf16 [C][R] ----------------
__global__ __launch_bounds__(256) void transpk(const float* __restrict__ in, u16* __restrict__ out,
                                               int R, int C) {
    __shared__ float tile[64][65];
    int c0 = blockIdx.x * 64, r0 = blockIdx.y * 64;
    int tid = threadIdx.x;
#pragma unroll
    for (int it = 0; it < 4; ++it) {
        int ci = it * 256 + tid;
        int r = ci >> 4, c4 = (ci & 15) * 4;
        float4 v = *(const float4*)&in[(size_t)(r0 + r) * C + c0 + c4];
        tile[r][c4 + 0] = v.x; tile[r][c4 + 1] = v.y; tile[r][c4 + 2] = v.z; tile[r][c4 + 3] = v.w;
    }
    __syncthreads();
#pragma unroll
    for (int it = 0; it < 4; ++it) {
        int ci = it * 256 + tid;
        int c = ci >> 4, rq = (ci & 15) * 4;
        ushort4 o;
        o.x = f2bf(tile[rq + 0][c]); o.y = f2bf(tile[rq + 1][c]);
        o.z = f2bf(tile[rq + 2][c]); o.w = f2bf(tile[rq + 3][c]);
        *(ushort4*)&out[(size_t)(c0 + c) * R + r0 + rq] = o;
    }
}

// ---------------- GEMM: C[M][N] = A[M][K] * Bt[N][K]^T, bf16 in, bf16 or f32 out ----------
// m97 structure + T2 both-sides swizzle (16-way -> 2-way bank conflicts).
template <int OUTF32>
__global__ __launch_bounds__(256) void gemm_bt(const u16* __restrict__ A, const u16* __restrict__ Bt,
                                               void* __restrict__ Cout, int M, int N, int K) {
    __shared__ __attribute__((aligned(16))) u16 at[128 * 64];
    __shared__ __attribute__((aligned(16))) u16 bt[128 * 64];
    int m0 = blockIdx.y * 128, n0 = blockIdx.x * 128;
    int tid = threadIdx.x;
    int lane = tid & 63, wid = tid >> 6;
    int wr = wid >> 1, wc = wid & 1;
    int l15 = lane & 15, g = lane >> 4;
    int sw = lane & 7;

    int srow = wid * 32 + (lane >> 3);
    int scol = ((lane & 7) ^ (lane >> 3)) * 8;   // swizzled global 16B-slot
    const u16* agp = &A[(size_t)(m0 + srow) * K + scol];
    const u16* bgp = &Bt[(size_t)(n0 + srow) * K + scol];

    f32x4 acc[4][4];
#pragma unroll
    for (int mi = 0; mi < 4; ++mi)
#pragma unroll
        for (int ni = 0; ni < 4; ++ni) acc[mi][ni] = (f32x4){0.f, 0.f, 0.f, 0.f};

    for (int kb = 0; kb < K; kb += 64) {
        __syncthreads();
#pragma unroll
        for (int c = 0; c < 4; ++c) {
            gload16(agp + (size_t)(c * 8) * K + kb, &at[(wid * 32 + c * 8) * 64]);
            gload16(bgp + (size_t)(c * 8) * K + kb, &bt[(wid * 32 + c * 8) * 64]);
        }
        __syncthreads();
#pragma unroll
        for (int ks = 0; ks < 2; ++ks) {
            bf16x8 af[4], bfr[4];
#pragma unroll
            for (int mi = 0; mi < 4; ++mi)
                af[mi] = *(const bf16x8*)&at[(wr * 64 + mi * 16 + l15) * 64 + (((ks * 4 + g) ^ sw) * 8)];
#pragma unroll
            for (int ni = 0; ni < 4; ++ni)
                bfr[ni] = *(const bf16x8*)&bt[(wc * 64 + ni * 16 + l15) * 64 + (((ks * 4 + g) ^ sw) * 8)];
#pragma unroll
            for (int mi = 0; mi < 4; ++mi)
#pragma unroll
                for (int ni = 0; ni < 4; ++ni)
                    acc[mi][ni] = __builtin_amdgcn_mfma_f32_16x16x32_bf16(af[mi], bfr[ni], acc[mi][ni], 0, 0, 0);
        }
    }
#pragma unroll
    for (int mi = 0; mi < 4; ++mi)
#pragma unroll
        for (int ni = 0; ni < 4; ++ni)
#pragma unroll
            for (int i = 0; i < 4; ++i) {
                int row = m0 + wr * 64 + mi * 16 + g * 4 + i;
                int col = n0 + wc * 64 + ni * 16 + l15;
                float v = acc[mi][ni][i];
                if (OUTF32) ((float*)Cout)[(size_t)row * N + col] = v;
                else        ((u16*)Cout)[(size_t)row * N + col] = f2bf(v);
            }
}

// ---------------- RoPE in-place on q,k slices of qkv (bf16) ----------------
__global__ __launch_bounds__(256) void ropek(u16* __restrict__ qkvb, const int* __restrict__ positions) {
    int t = blockIdx.x;
    float pos = (float)positions[t];
#pragma unroll
    for (int it = 0; it < 10; ++it) {
        int ci = it * 256 + threadIdx.x;        // 2560 = (NH+NKV)*64
        int hh = ci >> 6, d = ci & 63;
        int base = (hh < NH) ? hh * HD : KOFF + (hh - NH) * HD;
        size_t off = (size_t)t * QKVN + base + d;
        float x1 = bf2f(qkvb[off]);
        float x2 = bf2f(qkvb[off + 64]);
        float inv = powf(1.0e6f, -(float)d * (1.0f / 64.0f));
        float fr = pos * inv;
        float s = sinf(fr), c = cosf(fr);
        qkvb[off]      = f2bf(x1 * c - x2 * s);
        qkvb[off + 64] = f2bf(x2 * c + x1 * s);
    }
}

// ---------------- V^T materialization: qkv v-slice -> vT[NKV][HD][T] ----------------
__global__ __launch_bounds__(256) void vtranspk(const u16* __restrict__ qkvb, u16* __restrict__ vT) {
    __shared__ __attribute__((aligned(16))) u16 tile[64][136];
    int kvh = blockIdx.x, t0 = blockIdx.y * 64;
    int tid = threadIdx.x;
#pragma unroll
    for (int it = 0; it < 4; ++it) {
        int ci = it * 256 + tid;
        int r = ci >> 4, c8 = (ci & 15) * 8;
        *(bf16x8*)&tile[r][c8] = *(const bf16x8*)&qkvb[(size_t)(t0 + r) * QKVN + VOFF + kvh * HD + c8];
    }
    __syncthreads();
#pragma unroll
    for (int it = 0; it < 4; ++it) {
        int ci = it * 256 + tid;
        int d = ci >> 3, tc = (ci & 7) * 8;
        union { bf16x8 v; u16 u[8]; } o;
#pragma unroll
        for (int e = 0; e < 8; ++e) o.u[e] = tile[tc + e][d];
        *(bf16x8*)&vT[((size_t)kvh * HD + d) * T_TOK + t0 + tc] = o.v;
    }
}

// ---------------- Flash attention: block = (head, 64 q rows), 4 waves x 16 rows ------------
// R4: descending-qt dispatch (tail kill), T14 reg-prefetch of next K/V tile under compute,
//     T13 defer-max (THR=8), T5 setprio around MFMA clusters.
__global__ __launch_bounds__(256) void attnk(const u16* __restrict__ qkvb, const u16* __restrict__ vT,
                                             u16* __restrict__ attnb) {
    __shared__ __attribute__((aligned(16))) u16 kt_[64 * 136];
    __shared__ __attribute__((aligned(16))) u16 vt_[128 * 72];
    __shared__ __attribute__((aligned(16))) u16 pl_[4 * 16 * 72];
    int h = blockIdx.x, qt = 31 - blockIdx.y;   // long blocks first
    int kvh = h >> 2;
    int q0 = qt * 64;
    int tid = threadIdx.x, lane = tid & 63, wid = tid >> 6;
    int l15 = lane & 15, g = lane >> 4;
    const float scale = 0.08838834764831845f;

    // staging index precompute (per thread)
    int kr = tid >> 4, kc = (tid & 15) * 8;   // K: rows it*16+kr, 16B col kc
    int vd = tid >> 3, vc = (tid & 7) * 8;    // V: rows it*32+vd, 16B col vc
    const u16* kbase = qkvb + KOFF + (size_t)kvh * HD + kc;
    const u16* vbase = vT + ((size_t)kvh * HD) * T_TOK + vc;

    // Q fragments (held in registers for the whole block)
    bf16x8 qf[4];
    int qrow = q0 + wid * 16 + l15;
#pragma unroll
    for (int ks = 0; ks < 4; ++ks)
        qf[ks] = *(const bf16x8*)&qkvb[(size_t)qrow * QKVN + h * HD + ks * 32 + g * 8];

    f32x4 o[8];
#pragma unroll
    for (int df = 0; df < 8; ++df) o[df] = (f32x4){0.f, 0.f, 0.f, 0.f};
    float m_run[4], l_run[4];
#pragma unroll
    for (int i = 0; i < 4; ++i) { m_run[i] = -3.0e38f; l_run[i] = 0.f; }

    bf16x8 kreg[4], vreg[4];
    // prologue: tile 0 -> regs -> LDS; issue tile-1 loads
#pragma unroll
    for (int it = 0; it < 4; ++it)
        kreg[it] = *(const bf16x8*)&kbase[(size_t)(it * 16 + kr) * QKVN];
#pragma unroll
    for (int it = 0; it < 4; ++it)
        vreg[it] = *(const bf16x8*)&vbase[(size_t)(it * 32 + vd) * T_TOK];
#pragma unroll
    for (int it = 0; it < 4; ++it) *(bf16x8*)&kt_[(it * 16 + kr) * 136 + kc] = kreg[it];
#pragma unroll
    for (int it = 0; it < 4; ++it) *(bf16x8*)&vt_[(it * 32 + vd) * 72 + vc] = vreg[it];
    {
        int ktl = (1 <= qt) ? 1 : qt;
#pragma unroll
        for (int it = 0; it < 4; ++it)
            kreg[it] = *(const bf16x8*)&kbase[(size_t)(ktl * 64 + it * 16 + kr) * QKVN];
#pragma unroll
        for (int it = 0; it < 4; ++it)
            vreg[it] = *(const bf16x8*)&vbase[(size_t)(it * 32 + vd) * T_TOK + ktl * 64];
    }
    __syncthreads();

    for (int kt2 = 0; kt2 <= qt; ++kt2) {
        int kvb = kt2 * 64;

        // S = Q K^T  (per wave: 16 q rows x 64 kv cols)
        f32x4 s[4];
#pragma unroll
        for (int nf = 0; nf < 4; ++nf) s[nf] = (f32x4){0.f, 0.f, 0.f, 0.f};
        __builtin_amdgcn_s_setprio(1);
#pragma unroll
        for (int ks = 0; ks < 4; ++ks) {
#pragma unroll
            for (int nf = 0; nf < 4; ++nf) {
                bf16x8 bfr = *(const bf16x8*)&kt_[(nf * 16 + l15) * 136 + ks * 32 + g * 8];
                s[nf] = __builtin_amdgcn_mfma_f32_16x16x32_bf16(qf[ks], bfr, s[nf], 0, 0, 0);
            }
        }
        __builtin_amdgcn_s_setprio(0);

        // scale + causal mask + row max
        float mrow[4];
#pragma unroll
        for (int i = 0; i < 4; ++i) {
            int qr = q0 + wid * 16 + g * 4 + i;
            float mx = -3.0e38f;
#pragma unroll
            for (int nf = 0; nf < 4; ++nf) {
                int kvc = kvb + nf * 16 + l15;
                float v = s[nf][i] * scale;
                v = (kvc <= qr) ? v : -1.0e30f;
                s[nf][i] = v;
                mx = fmaxf(mx, v);
            }
            mrow[i] = mx;
        }
#pragma unroll
        for (int dd = 1; dd < 16; dd <<= 1)
#pragma unroll
            for (int i = 0; i < 4; ++i) mrow[i] = fmaxf(mrow[i], __shfl_xor(mrow[i], dd));

        // defer-max: if no row grew past m_run+8, keep old max and skip O-rescale
        int ok = 1;
#pragma unroll
        for (int i = 0; i < 4; ++i) ok &= (mrow[i] <= m_run[i] + 8.0f) ? 1 : 0;
        if (!__all(ok)) {
            float alpha[4];
#pragma unroll
            for (int i = 0; i < 4; ++i) {
                float mnew = fmaxf(m_run[i], mrow[i]);
                alpha[i] = __expf(m_run[i] - mnew);
                m_run[i] = mnew;
                l_run[i] *= alpha[i];
            }
#pragma unroll
            for (int df = 0; df < 8; ++df)
#pragma unroll
                for (int i = 0; i < 4; ++i) o[df][i] *= alpha[i];
        }

        // P = exp(S - m), row sums, stash P to LDS (per-wave region)
        float rsum[4] = {0.f, 0.f, 0.f, 0.f};
#pragma unroll
        for (int nf = 0; nf < 4; ++nf)
#pragma unroll
            for (int i = 0; i < 4; ++i) {
                float p = __expf(s[nf][i] - m_run[i]);
                rsum[i] += p;
                pl_[wid * 1152 + (g * 4 + i) * 72 + nf * 16 + l15] = f2bf(p);
            }
#pragma unroll
        for (int dd = 1; dd < 16; dd <<= 1)
#pragma unroll
            for (int i = 0; i < 4; ++i) rsum[i] += __shfl_xor(rsum[i], dd);
#pragma unroll
        for (int i = 0; i < 4; ++i) l_run[i] += rsum[i];

        // PV: O += P V   (A = P from LDS, B = V^T tile)
        __builtin_amdgcn_s_setprio(1);
#pragma unroll
        for (int ks2 = 0; ks2 < 2; ++ks2) {
            bf16x8 af = *(const bf16x8*)&pl_[wid * 1152 + l15 * 72 + ks2 * 32 + g * 8];
#pragma unroll
            for (int df = 0; df < 8; ++df) {
                bf16x8 bfr = *(const bf16x8*)&vt_[(df * 16 + l15) * 72 + ks2 * 32 + g * 8];
                o[df] = __builtin_amdgcn_mfma_f32_16x16x32_bf16(af, bfr, o[df], 0, 0, 0);
            }
        }
        __builtin_amdgcn_s_setprio(0);

        // stage next tile: regs (kt2+1, already in flight) -> LDS; issue loads for kt2+2
        if (kt2 < qt) {
            __syncthreads();   // everyone done reading LDS tile kt2
#pragma unroll
            for (int it = 0; it < 4; ++it) *(bf16x8*)&kt_[(it * 16 + kr) * 136 + kc] = kreg[it];
#pragma unroll
            for (int it = 0; it < 4; ++it) *(bf16x8*)&vt_[(it * 32 + vd) * 72 + vc] = vreg[it];
            int ktl = (kt2 + 2 <= qt) ? kt2 + 2 : qt;
#pragma unroll
            for (int it = 0; it < 4; ++it)
                kreg[it] = *(const bf16x8*)&kbase[(size_t)(ktl * 64 + it * 16 + kr) * QKVN];
#pragma unroll
            for (int it = 0; it < 4; ++it)
                vreg[it] = *(const bf16x8*)&vbase[(size_t)(it * 32 + vd) * T_TOK + ktl * 64];
            __syncthreads();   // tile kt2+1 ready
        }
    }

    // normalize + write
#pragma unroll
    for (int df = 0; df < 8; ++df)
#pragma unroll
        for (int i = 0; i < 4; ++i) {
            int qr = q0 + wid * 16 + g * 4 + i;
            int col = h * HD + df * 16 + l15;
            attnb[(size_t)qr * (NH * HD) + col] = f2bf(o[df][i] / l_run[i]);
        }
}

extern "C" void kernel_launch(void* const* d_in, const int* in_sizes, int n_in,
                              void* d_out, int out_size, void* d_ws, size_t ws_size,
                              hipStream_t stream) {
    const int*   positions = (const int*)d_in[0];
    const float* hs        = (const float*)d_in[1];
    const float* wqkv      = (const float*)d_in[2];
    const float* wo        = (const float*)d_in[3];
    float* out = (float*)d_out;

    char* ws = (char*)d_ws;
    u16* hsb   = (u16*)(ws);                                   // 16,777,216  (reused as attnb)
    u16* wqkvT = (u16*)(ws + 16777216);                        // 50,331,648
    u16* woT   = (u16*)(ws + 16777216 + 50331648);             // 33,554,432
    u16* qkvb  = (u16*)(ws + 16777216 + 50331648 + 33554432);  // 25,165,824
    u16* vT    = (u16*)(ws + 16777216 + 50331648 + 33554432 + 25165824); // 4,194,304
    u16* attnb = hsb;

    convk<<<8192, 256, 0, stream>>>(hs, hsb);
    transpk<<<dim3(96, 64), 256, 0, stream>>>(wqkv, wqkvT, HID, QKVN);
    transpk<<<dim3(64, 64), 256, 0, stream>>>(wo, woT, HID, HID);

    gemm_bt<0><<<dim3(48, 16), 256, 0, stream>>>(hsb, wqkvT, qkvb, T_TOK, QKVN, HID);

    ropek<<<T_TOK, 256, 0, stream>>>(qkvb, positions);

    vtranspk<<<dim3(NKV, 32), 256, 0, stream>>>(qkvb, vT);

    attnk<<<dim3(NH, 32), 256, 0, stream>>>(qkvb, vT, attnb);

    gemm_bt<1><<<dim3(32, 16), 256, 0, stream>>>(attnb, woT, out, T_TOK, HID, HID);
}